// Round 4
// baseline (29375.589 us; speedup 1.0000x reference)
//
#include <hip/hip_runtime.h>
#include <stdint.h>

#define Bsz 64
#define Tsz 1024
#define NIc 128
#define NHc 512
#define DTc 0.1f
#define GRID 256   // prologue spread over all CUs
#define NPW 8      // persistent WGs (1 per XCD), zero inter-WG sync in recurrence
#define BPW 8      // batches per persistent WG

typedef __attribute__((ext_vector_type(8))) short short8;
typedef __attribute__((ext_vector_type(4))) float f32x4;
typedef unsigned long long u64_t;

__device__ __forceinline__ unsigned short f2bf(float f) {
  union { float f; uint32_t u; } v; v.f = f;
  return (unsigned short)((v.u + 0x7fffu + ((v.u >> 16) & 1u)) >> 16);
}
__device__ __forceinline__ float bf2f(unsigned short h) {
  union { float f; uint32_t u; } v; v.u = ((uint32_t)h) << 16; return v.f;
}
__device__ __forceinline__ float fast_tanh(float xx) {
  float a = __builtin_fabsf(xx);
  float e = __expf(-2.0f * a);
  float r = (1.0f - e) / (1.0f + e);
  return __builtin_copysignf(r, xx);
}

__global__ __launch_bounds__(512, 2)
void pirn_kernel(const float* __restrict__ x, const float* __restrict__ x2h,
                 const float* __restrict__ h2h, const float* __restrict__ bias,
                 const float* __restrict__ gam_p, const float* __restrict__ eps_p,
                 float* __restrict__ out, char* __restrict__ ws)
{
  __shared__ __align__(16) char lds[34816];
  const int g    = blockIdx.x;
  const int tid  = threadIdx.x;
  const int lane = tid & 63;
  const int wv   = tid >> 6;    // 0..7
  const int l15  = lane & 15;
  const int quad = lane >> 4;

  unsigned char* prolflags = (unsigned char*)ws;                       // [256]
  unsigned short* hcolT = (unsigned short*)(ws + 4096);                // [512][512]: bf(h2h[k][n]) at [n][k]
  unsigned short* hrowB = (unsigned short*)(ws + 4096 + 524288);       // [512][512]: bf(h2h[n][k]) at [n][k]

  // ---------------- prologue: out[b,t,:] = tanh(x[b,t,:] @ x2h) ----------------
  // WG g owns rows [g*256, (g+1)*256) of (B*T, H). 8 waves, 2 row-tiles each.
  {
    unsigned short* x2ht_hi = (unsigned short*)lds;             // [64][136]
    unsigned short* x2ht_lo = (unsigned short*)(lds + 17408);   // [64][136]
    const long R0 = (long)g * 256;
    for (int pass = 0; pass < 8; ++pass) {
      const int c0 = pass * 64;
      __syncthreads();
      for (int i = tid; i < 64 * NIc; i += 512) {
        int c = i & 63; int k = i >> 6;
        float v = x2h[k * NHc + c0 + c];
        unsigned short hi = f2bf(v);
        x2ht_hi[c * 136 + k] = hi;
        x2ht_lo[c * 136 + k] = f2bf(v - bf2f(hi));
      }
      __syncthreads();
      for (int mt = wv * 2; mt < wv * 2 + 2; ++mt) {
        const float* xr = x + (R0 + mt * 16 + l15) * NIc;
        short8 ahi[4], alo[4];
#pragma unroll
        for (int kb = 0; kb < 4; ++kb) {
          int k0 = kb * 32 + quad * 8;
          f32x4 v0 = *(const f32x4*)(xr + k0);
          f32x4 v1 = *(const f32x4*)(xr + k0 + 4);
#pragma unroll
          for (int e = 0; e < 4; ++e) {
            unsigned short h0 = f2bf(v0[e]);
            ahi[kb][e] = (short)h0;
            alo[kb][e] = (short)f2bf(v0[e] - bf2f(h0));
            unsigned short h1 = f2bf(v1[e]);
            ahi[kb][e + 4] = (short)h1;
            alo[kb][e + 4] = (short)f2bf(v1[e] - bf2f(h1));
          }
        }
#pragma unroll
        for (int nt = 0; nt < 4; ++nt) {
          f32x4 acc0 = {0.f, 0.f, 0.f, 0.f};
          f32x4 acc1 = {0.f, 0.f, 0.f, 0.f};
#pragma unroll
          for (int kb = 0; kb < 4; ++kb) {
            int k0 = kb * 32 + quad * 8;
            short8 bhi = *(const short8*)(x2ht_hi + (nt * 16 + l15) * 136 + k0);
            short8 blo = *(const short8*)(x2ht_lo + (nt * 16 + l15) * 136 + k0);
            acc0 = __builtin_amdgcn_mfma_f32_16x16x32_bf16(ahi[kb], bhi, acc0, 0, 0, 0);
            acc1 = __builtin_amdgcn_mfma_f32_16x16x32_bf16(alo[kb], bhi, acc1, 0, 0, 0);
            acc0 = __builtin_amdgcn_mfma_f32_16x16x32_bf16(ahi[kb], blo, acc0, 0, 0, 0);
          }
          long orow = R0 + mt * 16 + quad * 4;
          int oc = c0 + nt * 16 + l15;
#pragma unroll
          for (int r = 0; r < 4; ++r)
            out[(orow + r) * NHc + oc] = fast_tanh(acc0[r] + acc1[r]);
        }
      }
    }
  }

  // h2h -> bf16 copies (slice per persistent WG; consumed by all 8 after barrier)
  if (g < NPW) {
    for (int i = tid; i < 32768; i += 512) {
      int idx = g * 32768 + i;
      hrowB[idx] = f2bf(h2h[idx]);          // [n][k] = h2h row-major directly
    }
    for (int i = tid; i < 32768; i += 512) {
      int n = g * 64 + (i & 63);
      int k = i >> 6;
      hcolT[n * 512 + k] = f2bf(h2h[k * 512 + n]);
    }
  }

  // release prologue + conversion stores (one wbL2 per WG), arrive via byte flag
  __syncthreads();
  if (tid == 0) {
    __builtin_amdgcn_fence(__ATOMIC_RELEASE, "agent");
    __hip_atomic_store(&prolflags[g], (unsigned char)1, __ATOMIC_RELAXED,
                       __HIP_MEMORY_SCOPE_AGENT);
  }
  if (g >= NPW) return;  // prologue-only WGs done

  // ---- the ONLY global barrier: wait 256 flags, then one acquire fence ----
  {
    const u64_t* pf = (const u64_t*)prolflags;
    if (tid < 64) {
      bool done;
      do {
        bool ok = true;
        if (lane < 32) {
          u64_t v = __hip_atomic_load(&pf[lane], __ATOMIC_RELAXED,
                                      __HIP_MEMORY_SCOPE_AGENT);
          ok = (v == 0x0101010101010101ull);
        }
        done = __all(ok);
        if (!done) __builtin_amdgcn_s_sleep(8);
      } while (!done);
    }
    __syncthreads();
    __builtin_amdgcn_fence(__ATOMIC_ACQUIRE, "agent");
  }

  // ---------------- persistent recurrence: WG g owns batches [g*8, g*8+8) ----------------
  // All data now WG-private or read-only; plain cached loads/stores only.
  unsigned short* hyL = (unsigned short*)lds;             // [16][520] bf16 (rows 8..15 pad)
  unsigned short* prL = (unsigned short*)(lds + 16640);   // [16][520] bf16
  for (int i = tid; i < 8320; i += 512) ((uint32_t*)lds)[i] = 0;

  const int b0 = g * BPW;
  const int rq = quad * 4;                 // local C/D row base (0..12)
  const bool act = quad < 2;               // rows 8..15 are padding
  const int bsafe = b0 + (quad & 1) * 4;   // clamped batch base for pad-quad u loads
  int   ncol[4];
  float bias4[4], gm4[4], ep4[4];
#pragma unroll
  for (int nt = 0; nt < 4; ++nt) {
    int n = wv * 64 + nt * 16 + l15;
    ncol[nt]  = n;
    bias4[nt] = bias[n];
    gm4[nt]   = gam_p[n];
    ep4[nt]   = eps_p[n];
  }
  float hy_s[16], hz_s[16];
#pragma unroll
  for (int i = 0; i < 16; ++i) { hy_s[i] = 0.f; hz_s[i] = 0.f; }
  __syncthreads();

  for (int t = 0; t < Tsz; ++t) {
    // forcing term u (written by prologue; overwritten by hy below — same lane)
    float u_s[16];
#pragma unroll
    for (int nt = 0; nt < 4; ++nt)
#pragma unroll
      for (int r = 0; r < 4; ++r)
        u_s[nt * 4 + r] = out[((long)(bsafe + r) * Tsz + t) * NHc + ncol[nt]];

    // phase 1: pre = tanh(hy @ h2h + bias). A from LDS hy (zeros at t=0), B from L2.
    short8 a1[16];
#pragma unroll
    for (int kb = 0; kb < 16; ++kb)
      a1[kb] = *(const short8*)(hyL + l15 * 520 + kb * 32 + quad * 8);
#pragma unroll
    for (int nt = 0; nt < 4; ++nt) {
      short8 bf[16];
#pragma unroll
      for (int kb = 0; kb < 16; ++kb)
        bf[kb] = *(const short8*)(hcolT + ncol[nt] * 512 + kb * 32 + quad * 8);
      f32x4 ae = {0.f, 0.f, 0.f, 0.f}, ao = {0.f, 0.f, 0.f, 0.f};
#pragma unroll
      for (int kb = 0; kb < 16; kb += 2) {
        ae = __builtin_amdgcn_mfma_f32_16x16x32_bf16(a1[kb],     bf[kb],     ae, 0, 0, 0);
        ao = __builtin_amdgcn_mfma_f32_16x16x32_bf16(a1[kb + 1], bf[kb + 1], ao, 0, 0, 0);
      }
#pragma unroll
      for (int r = 0; r < 4; ++r) {
        float pre = fast_tanh(ae[r] + ao[r] + bias4[nt]);
        prL[(rq + r) * 520 + ncol[nt]] = f2bf(pre);
      }
    }
    __syncthreads();  // prL complete (all waves)

    // phase 2: C2 = pre @ h2h^T, then state update.
    short8 a2[16];
#pragma unroll
    for (int kb = 0; kb < 16; ++kb)
      a2[kb] = *(const short8*)(prL + l15 * 520 + kb * 32 + quad * 8);
#pragma unroll
    for (int nt = 0; nt < 4; ++nt) {
      short8 bf[16];
#pragma unroll
      for (int kb = 0; kb < 16; ++kb)
        bf[kb] = *(const short8*)(hrowB + ncol[nt] * 512 + kb * 32 + quad * 8);
      f32x4 ce = {0.f, 0.f, 0.f, 0.f}, co = {0.f, 0.f, 0.f, 0.f};
#pragma unroll
      for (int kb = 0; kb < 16; kb += 2) {
        ce = __builtin_amdgcn_mfma_f32_16x16x32_bf16(a2[kb],     bf[kb],     ce, 0, 0, 0);
        co = __builtin_amdgcn_mfma_f32_16x16x32_bf16(a2[kb + 1], bf[kb + 1], co, 0, 0, 0);
      }
#pragma unroll
      for (int r = 0; r < 4; ++r) {
        const int i = nt * 4 + r;
        float c2 = ce[r] + co[r];
        float hz = hz_s[i] + DTc * (u_s[i] - c2 - gm4[nt] * hy_s[i] - ep4[nt] * hz_s[i]);
        hz_s[i] = hz;
        hy_s[i] += DTc * hz;
        if (act)
          out[((long)(b0 + rq + r) * Tsz + t) * NHc + ncol[nt]] = hy_s[i];
        hyL[(rq + r) * 520 + ncol[nt]] = f2bf(hy_s[i]);
      }
    }
    __syncthreads();  // hyL complete for next phase 1
  }

  // final hy tail
#pragma unroll
  for (int nt = 0; nt < 4; ++nt)
#pragma unroll
    for (int r = 0; r < 4; ++r)
      if (act)
        out[(long)Bsz * Tsz * NHc + (long)(b0 + rq + r) * NHc + ncol[nt]] = hy_s[nt * 4 + r];
}

extern "C" void kernel_launch(void* const* d_in, const int* in_sizes, int n_in,
                              void* d_out, int out_size, void* d_ws, size_t ws_size,
                              hipStream_t stream) {
  const float* x    = (const float*)d_in[0];
  const float* x2h  = (const float*)d_in[1];
  const float* h2h  = (const float*)d_in[2];
  const float* bias = (const float*)d_in[3];
  const float* gam  = (const float*)d_in[4];
  const float* eps  = (const float*)d_in[5];
  (void)in_sizes; (void)n_in; (void)out_size; (void)ws_size;
  pirn_kernel<<<dim3(GRID), dim3(512), 0, stream>>>(
      x, x2h, h2h, bias, gam, eps, (float*)d_out, (char*)d_ws);
}